// Round 19
// baseline (448.528 us; speedup 1.0000x reference)
//
#include <hip/hip_runtime.h>
#include <math.h>

#define NTH 256
#define QHSTR 64    // Q/K/V f16 stride (halves): head h at col h*8 (7+1 pad)
#define FSTR 136    // FB chunk stride (ushorts): 112 real + 16 zero-pad + 8 unused
#define LOG2E 1.4426950408889634f

typedef __attribute__((ext_vector_type(8))) short short8;
typedef __attribute__((ext_vector_type(4))) float f32x4;
typedef _Float16 half2_t __attribute__((ext_vector_type(2)));

__device__ __forceinline__ half2_t as_h2(unsigned int u) {
    return __builtin_bit_cast(half2_t, u);
}
__device__ __forceinline__ float fast_exp2(float x) {
    float r;
    asm("v_exp_f32 %0, %1" : "=v"(r) : "v"(x));
    return r;
}
__device__ __forceinline__ unsigned short f2bf(float x) {          // RNE (prep only)
    unsigned int u = __float_as_uint(x);
    return (unsigned short)((u + 0x7FFFu + ((u >> 16) & 1u)) >> 16);
}
__device__ __forceinline__ unsigned short f2bf_t(float x) {        // truncate (MFMA inputs only)
    return (unsigned short)(__float_as_uint(x) >> 16);
}

__host__ __device__ constexpr int pc_(int v) { int c = 0; while (v) { c += v & 1; v >>= 1; } return c; }
__host__ __device__ constexpr int gp_sign(int a, int b) {
    int s = 0; int t = a >> 1;
    while (t) { s += pc_(t & b); t >>= 1; }
    return (s & 1) ? -1 : 1;
}
#define BLADE(i) ((int)((0x76534210u >> ((i) * 4)) & 0xF))

__device__ __forceinline__ float gelu_sig(float z) {
    float E = fast_exp2(-2.4554669f * z);
    return z * __builtin_amdgcn_rcpf(1.0f + E);
}

// ---------------- weight prep: bf16, transposed, zero-padded ----------------
// ws layout (ushorts): [0, L*16384) qkvo [(l*4+mat)*64+n]*64+k
//                      [+, L*14336) w1t  [(l*224+n)*64+k]
//                      [+, L*16384) w2t  [(l*64+n)*256+k]  (k<224 real, else 0)
__global__ void prep_weights(const float* __restrict__ Wq, const float* __restrict__ Wk,
                             const float* __restrict__ Wv, const float* __restrict__ Wo,
                             const float* __restrict__ W1, const float* __restrict__ W2,
                             unsigned short* __restrict__ ws, int L)
{
    int idx = blockIdx.x * NTH + threadIdx.x;
    int total1 = L * 16384, total2 = L * 14336, total3 = L * 16384;
    if (idx < total1) {
        int k = idx & 63, n = (idx >> 6) & 63, mat = (idx >> 12) & 3, l = idx >> 14;
        float v = 0.f;
        if (k < 56 && n < 56) {
            const float* W = (mat == 0) ? Wq : (mat == 1) ? Wk : (mat == 2) ? Wv : Wo;
            v = W[l * 3136 + k * 56 + n];
            if (mat == 0) v *= 0.3779644730092272f * LOG2E;  // 1/sqrt(7) and log2e folded
        }
        ws[idx] = f2bf(v);
    } else if (idx < total1 + total2) {
        int t = idx - total1;
        int k = t & 63, n = (t >> 6) % 224, l = t / 14336;
        float v = (k < 56) ? W1[l * 12544 + k * 224 + n] : 0.f;
        ws[idx] = f2bf(v);
    } else if (idx < total1 + total2 + total3) {
        int t = idx - total1 - total2;
        int k = t & 255, n = (t >> 8) & 63, l = t >> 14;
        float v = (k < 224 && n < 56) ? W2[l * 12544 + k * 56 + n] : 0.f;
        ws[idx] = f2bf(v);
    }
}

__global__ __launch_bounds__(NTH, 5) void nbody_fused(
    const float* __restrict__ nodes, const float* __restrict__ edges,
    const float* __restrict__ src_mask,
    const float* __restrict__ W_in, const float* __restrict__ b_in,
    const float* __restrict__ W_gp, const float* __restrict__ b_gp,
    const float* __restrict__ ln1g, const float* __restrict__ ln1b,
    const float* __restrict__ ln2g, const float* __restrict__ ln2b,
    const float* __restrict__ b1, const float* __restrict__ b2,
    const unsigned short* __restrict__ ws, int L, int Btot,
    float* __restrict__ out)
{
    // 5600 + 7200 + 19200 = 32000 B -> 5 blocks/CU
    __shared__ __align__(16) _Float16 XSH[2][1400];           // residual f16 [25][56] (RNE cvt RMW)
    __shared__ __align__(16) unsigned short HB[2][1800];      // h bf16 [25][72], cols56-63 zero
    __shared__ __align__(16) unsigned short UNI[2][4800];     // QKV-f16 [3][25][64] / FB [25][136] / staging

    const int b0 = blockIdx.x * 2, tid = threadIdx.x;
    const int lane = tid & 63, wid = tid >> 6;
    const int nl = lane & 15, quad = lane >> 4;
    const int col = wid * 16 + nl;
    const int pcolh = (col / 7) * 8 + col % 7;
    const int ln_p = lane & 7;
    const int ln_s = wid + 4 * (lane >> 3);                // fused-LN row (valid if <25)
    int rA1 = 16 + nl; if (rA1 > 24) rA1 = 24;             // clamped A-row for tile 1
    const int bbm1 = (b0 + 1 < Btot) ? (b0 + 1) : (Btot - 1);

    // ---- P0: load src (f16) for both samples; zero HB k-pads ----
    for (int t = tid; t < 1200; t += NTH) {
        int ss = t / 600, r0 = t - ss * 600;
        int s = r0 / 24, r = r0 % 24;
        int bb = b0 + ss;
        if (bb < Btot)
            XSH[ss][r0] = (_Float16)((s < 5) ? nodes[bb * 120 + r0] : edges[bb * 480 + (s - 5) * 24 + r]);
    }
    for (int t = tid; t < 400; t += NTH) {
        int ss = t / 200, r0 = t - ss * 200;
        int r = r0 >> 3, c = 56 + (r0 & 7);
        HB[ss][r * 72 + c] = 0;
    }
    __syncthreads();

    // ---- P1: src_mv -> KBs f16 (per sample) ----
    #pragma unroll
    for (int ss = 0; ss < 2; ss++) {
        _Float16* KBs = (_Float16*)UNI[ss];
        for (int t = tid; t < 1400; t += NTH) {
            int s = t / 56, rem = t % 56, n = rem >> 3, i = rem & 7;
            int g = __popc(BLADE(i));
            float acc = (i == 0) ? b_in[n] : 0.0f;
            #pragma unroll
            for (int m = 0; m < 3; m++)
                acc += (float)XSH[ss][s * 24 + m * 8 + i] * W_in[n * 12 + m * 4 + g];
            KBs[s * 56 + rem] = (_Float16)acc;
        }
    }
    __syncthreads();

    // ---- P2: geometric product -> VBs f16 ----
    #pragma unroll
    for (int ss = 0; ss < 2; ss++) {
        _Float16* KBs = (_Float16*)UNI[ss];
        _Float16* VBs = KBs + 1400;
        for (int t = tid; t < 175; t += NTH) {
            int s = t / 7, n = t % 7;
            float m8[8], g8[8];
            #pragma unroll
            for (int i = 0; i < 8; i++) { m8[i] = (float)KBs[s * 56 + n * 8 + i]; g8[i] = 0.0f; }
            #pragma unroll
            for (int ai = 0; ai < 8; ai++) {
                const int a = BLADE(ai);
                #pragma unroll
                for (int bi = 0; bi < 8; bi++) {
                    const int bb = BLADE(bi);
                    const int j = BLADE(a ^ bb);
                    const int sg = gp_sign(a, bb);
                    g8[j] += (sg > 0) ? (m8[ai] * m8[bi]) : (-m8[ai] * m8[bi]);
                }
            }
            #pragma unroll
            for (int j = 0; j < 8; j++) VBs[s * 56 + n * 8 + j] = (_Float16)g8[j];
        }
    }
    __syncthreads();

    // ---- P3: src2 -> XSH f16 ----
    #pragma unroll
    for (int ss = 0; ss < 2; ss++) {
        const _Float16* KBs = (const _Float16*)UNI[ss];
        const _Float16* VBs = KBs + 1400;
        for (int t = tid; t < 1400; t += NTH) {
            int s = t / 56, rem = t % 56, n = rem >> 3, i = rem & 7;
            int g = __popc(BLADE(i));
            float acc = (i == 0) ? b_gp[n] : 0.0f;
            #pragma unroll
            for (int m = 0; m < 7; m++)
                acc += (float)KBs[s * 56 + m * 8 + i] * W_gp[n * 56 + m * 4 + g];
            #pragma unroll
            for (int m = 0; m < 7; m++)
                acc += (float)VBs[s * 56 + m * 8 + i] * W_gp[n * 56 + (7 + m) * 4 + g];
            XSH[ss][s * 56 + rem] = (_Float16)acc;
        }
    }
    __syncthreads();

    const unsigned short* w1t_all = ws + (size_t)L * 16384;
    const unsigned short* w2t_all = w1t_all + (size_t)L * 14336;

    for (int l = 0; l < L; l++) {
        const float* g1 = ln1g + l * 56; const float* e1 = ln1b + l * 56;
        const float* g2 = ln2g + l * 56; const float* e2 = ln2b + l * 56;

        // ---- fused LN1 (both samples) + zero Q/K head-pads ----
        if (tid < 200) {
            int s = tid >> 3, hh = tid & 7;
            #pragma unroll
            for (int ss = 0; ss < 2; ss++) {
                _Float16* QH = (_Float16*)UNI[ss];
                _Float16* KH = QH + 25 * QHSTR;
                QH[s * QHSTR + hh * 8 + 7] = (_Float16)0.f;
                KH[s * QHSTR + hh * 8 + 7] = (_Float16)0.f;
            }
        }
        #pragma unroll
        for (int ss = 0; ss < 2; ss++) {
            float x[7]; float sum = 0.f, sq = 0.f;
            if (ln_s < 25) {
                const _Float16* xp = XSH[ss] + ln_s * 56 + ln_p * 7;
                #pragma unroll
                for (int j = 0; j < 7; j++) { x[j] = (float)xp[j]; sum += x[j]; sq += x[j] * x[j]; }
            }
            #pragma unroll
            for (int off = 1; off < 8; off <<= 1) {
                sum += __shfl_xor(sum, off, 64);
                sq  += __shfl_xor(sq,  off, 64);
            }
            if (ln_s < 25) {
                float mean = sum * (1.0f / 56.0f);
                float rs = __builtin_amdgcn_rsqf(sq * (1.0f / 56.0f) - mean * mean + 1e-5f);
                unsigned short* hp = HB[ss] + ln_s * 72 + ln_p * 7;
                #pragma unroll
                for (int j = 0; j < 7; j++) {
                    int d = ln_p * 7 + j;
                    hp[j] = f2bf_t((x[j] - mean) * rs * g1[d] + e1[d]);
                }
            }
        }
        __syncthreads();

        // ---- QKV via MFMA: shared B-frags, dual-sample A (clamped A rows) ----
        {
            short8 a[2][2][2];   // [ss][mt][ks]
            #pragma unroll
            for (int ss = 0; ss < 2; ss++)
                #pragma unroll
                for (int ks = 0; ks < 2; ks++) {
                    a[ss][0][ks] = *(const short8*)(HB[ss] + nl * 72 + ks * 32 + quad * 8);
                    a[ss][1][ks] = *(const short8*)(HB[ss] + rA1 * 72 + ks * 32 + quad * 8);
                }
            #pragma unroll
            for (int mat = 0; mat < 3; mat++) {
                const unsigned short* bp = ws + (((size_t)(l * 4 + mat)) << 12) + (((size_t)col) << 6) + quad * 8;
                short8 b0f = *(const short8*)(bp);
                short8 b1f = *(const short8*)(bp + 32);
                #pragma unroll
                for (int ss = 0; ss < 2; ss++) {
                    f32x4 acc0 = {0, 0, 0, 0}, acc1 = {0, 0, 0, 0};
                    acc0 = __builtin_amdgcn_mfma_f32_16x16x32_bf16(a[ss][0][0], b0f, acc0, 0, 0, 0);
                    acc0 = __builtin_amdgcn_mfma_f32_16x16x32_bf16(a[ss][0][1], b1f, acc0, 0, 0, 0);
                    acc1 = __builtin_amdgcn_mfma_f32_16x16x32_bf16(a[ss][1][0], b0f, acc1, 0, 0, 0);
                    acc1 = __builtin_amdgcn_mfma_f32_16x16x32_bf16(a[ss][1][1], b1f, acc1, 0, 0, 0);
                    _Float16* dst = (_Float16*)UNI[ss] + mat * 25 * QHSTR;
                    if (col < 56) {
                        #pragma unroll
                        for (int r = 0; r < 4; r++) {
                            int row0 = quad * 4 + r;
                            dst[row0 * QHSTR + pcolh] = (_Float16)acc0[r];
                            int row1 = 16 + row0;
                            if (row1 < 25) dst[row1 * QHSTR + pcolh] = (_Float16)acc1[r];
                        }
                    }
                }
            }
        }
        __syncthreads();

        // ---- attention: dual-sample interleaved; mask from global (L2-hot) ----
        if (tid < 200) {
            int s = tid >> 3, hh = tid & 7;
            const _Float16* QHa = (const _Float16*)UNI[0];
            const _Float16* QHb = (const _Float16*)UNI[1];
            const _Float16* KHa = QHa + 25 * QHSTR, * VHa = KHa + 25 * QHSTR;
            const _Float16* KHb = QHb + 25 * QHSTR, * VHb = KHb + 25 * QHSTR;
            const float* mka = src_mask + (size_t)b0 * 625 + s * 25;
            const float* mkb = src_mask + (size_t)bbm1 * 625 + s * 25;
            uint4 Qa = *(const uint4*)(QHa + s * QHSTR + hh * 8);
            uint4 Qb = *(const uint4*)(QHb + s * QHSTR + hh * 8);
            half2_t qa0 = as_h2(Qa.x), qa1 = as_h2(Qa.y), qa2 = as_h2(Qa.z), qa3 = as_h2(Qa.w);
            half2_t qb0 = as_h2(Qb.x), qb1 = as_h2(Qb.y), qb2 = as_h2(Qb.z), qb3 = as_h2(Qb.w);
            float lsa = 0.f, lsb = 0.f;
            half2_t aa0 = {0,0}, aa1 = {0,0}, aa2 = {0,0}, aa3 = {0,0};
            half2_t ab0 = {0,0}, ab1 = {0,0}, ab2 = {0,0}, ab3 = {0,0};
            for (int kk = 0; kk < 25; kk++) {
                uint4 Ka = *(const uint4*)(KHa + kk * QHSTR + hh * 8);
                uint4 Kb = *(const uint4*)(KHb + kk * QHSTR + hh * 8);
                float da = mka[kk] * LOG2E;
                float db = mkb[kk] * LOG2E;
                da = __builtin_amdgcn_fdot2(qa3, as_h2(Ka.w), da, false);
                db = __builtin_amdgcn_fdot2(qb3, as_h2(Kb.w), db, false);
                da = __builtin_amdgcn_fdot2(qa2, as_h2(Ka.z), da, false);
                db = __builtin_amdgcn_fdot2(qb2, as_h2(Kb.z), db, false);
                da = __builtin_amdgcn_fdot2(qa1, as_h2(Ka.y), da, false);
                db = __builtin_amdgcn_fdot2(qb1, as_h2(Kb.y), db, false);
                da = __builtin_amdgcn_fdot2(qa0, as_h2(Ka.x), da, false);
                db = __builtin_amdgcn_fdot2(qb0, as_h2(Kb.x), db, false);
                float pa = fast_exp2(da);
                float pb = fast_exp2(db);
                lsa += pa; lsb += pb;
                uint4 Va = *(const uint4*)(VHa + kk * QHSTR + hh * 8);
                uint4 Vb = *(const uint4*)(VHb + kk * QHSTR + hh * 8);
                _Float16 pha = (_Float16)pa, phb = (_Float16)pb;
                half2_t p2a = {pha, pha}, p2b = {phb, phb};
                aa0 += p2a * as_h2(Va.x); aa1 += p2a * as_h2(Va.y);
                aa2 += p2a * as_h2(Va.z); aa3 += p2a * as_h2(Va.w);
                ab0 += p2b * as_h2(Vb.x); ab1 += p2b * as_h2(Vb.y);
                ab2 += p2b * as_h2(Vb.z); ab3 += p2b * as_h2(Vb.w);
            }
            float inva = __builtin_amdgcn_rcpf(lsa);
            float invb = __builtin_amdgcn_rcpf(lsb);
            unsigned short* opa = HB[0] + s * 72 + hh * 7;
            unsigned short* opb = HB[1] + s * 72 + hh * 7;
            opa[0] = f2bf_t((float)aa0.x * inva); opa[1] = f2bf_t((float)aa0.y * inva);
            opa[2] = f2bf_t((float)aa1.x * inva); opa[3] = f2bf_t((float)aa1.y * inva);
            opa[4] = f2bf_t((float)aa2.x * inva); opa[5] = f2bf_t((float)aa2.y * inva);
            opa[6] = f2bf_t((float)aa3.x * inva);
            opb[0] = f2bf_t((float)ab0.x * invb); opb[1] = f2bf_t((float)ab0.y * invb);
            opb[2] = f2bf_t((float)ab1.x * invb); opb[3] = f2bf_t((float)ab1.y * invb);
            opb[4] = f2bf_t((float)ab2.x * invb); opb[5] = f2bf_t((float)ab2.y * invb);
            opb[6] = f2bf_t((float)ab3.x * invb);
        }
        __syncthreads();

        // ---- x += o @ Wo (shared B-frags, clamped A rows; f16 RNE RMW) ----
        {
            short8 a[2][2][2];
            #pragma unroll
            for (int ss = 0; ss < 2; ss++)
                #pragma unroll
                for (int ks = 0; ks < 2; ks++) {
                    a[ss][0][ks] = *(const short8*)(HB[ss] + nl * 72 + ks * 32 + quad * 8);
                    a[ss][1][ks] = *(const short8*)(HB[ss] + rA1 * 72 + ks * 32 + quad * 8);
                }
            const unsigned short* bp = ws + (((size_t)(l * 4 + 3)) << 12) + (((size_t)col) << 6) + quad * 8;
            short8 b0f = *(const short8*)(bp);
            short8 b1f = *(const short8*)(bp + 32);
            #pragma unroll
            for (int ss = 0; ss < 2; ss++) {
                f32x4 acc0 = {0, 0, 0, 0}, acc1 = {0, 0, 0, 0};
                acc0 = __builtin_amdgcn_mfma_f32_16x16x32_bf16(a[ss][0][0], b0f, acc0, 0, 0, 0);
                acc0 = __builtin_amdgcn_mfma_f32_16x16x32_bf16(a[ss][0][1], b1f, acc0, 0, 0, 0);
                acc1 = __builtin_amdgcn_mfma_f32_16x16x32_bf16(a[ss][1][0], b0f, acc1, 0, 0, 0);
                acc1 = __builtin_amdgcn_mfma_f32_16x16x32_bf16(a[ss][1][1], b1f, acc1, 0, 0, 0);
                if (col < 56) {
                    #pragma unroll
                    for (int r = 0; r < 4; r++) {
                        int row0 = quad * 4 + r;
                        _Float16* xp0 = &XSH[ss][row0 * 56 + col];
                        *xp0 = (_Float16)((float)*xp0 + acc0[r]);
                        int row1 = 16 + row0;
                        if (row1 < 25) {
                            _Float16* xp1 = &XSH[ss][row1 * 56 + col];
                            *xp1 = (_Float16)((float)*xp1 + acc1[r]);
                        }
                    }
                }
            }
        }
        __syncthreads();

        // ---- fused LN2 ----
        #pragma unroll
        for (int ss = 0; ss < 2; ss++) {
            float x[7]; float sum = 0.f, sq = 0.f;
            if (ln_s < 25) {
                const _Float16* xp = XSH[ss] + ln_s * 56 + ln_p * 7;
                #pragma unroll
                for (int j = 0; j < 7; j++) { x[j] = (float)xp[j]; sum += x[j]; sq += x[j] * x[j]; }
            }
            #pragma unroll
            for (int off = 1; off < 8; off <<= 1) {
                sum += __shfl_xor(sum, off, 64);
                sq  += __shfl_xor(sq,  off, 64);
            }
            if (ln_s < 25) {
                float mean = sum * (1.0f / 56.0f);
                float rs = __builtin_amdgcn_rsqf(sq * (1.0f / 56.0f) - mean * mean + 1e-5f);
                unsigned short* hp = HB[ss] + ln_s * 72 + ln_p * 7;
                #pragma unroll
                for (int j = 0; j < 7; j++) {
                    int d = ln_p * 7 + j;
                    hp[j] = f2bf_t((x[j] - mean) * rs * g2[d] + e2[d]);
                }
            }
        }
        __syncthreads();

        // ---- FFN in two 112-col chunks ----
        {
            short8 a[2][2][2];
            #pragma unroll
            for (int ss = 0; ss < 2; ss++)
                #pragma unroll
                for (int ks = 0; ks < 2; ks++) {
                    a[ss][0][ks] = *(const short8*)(HB[ss] + nl * 72 + ks * 32 + quad * 8);
                    a[ss][1][ks] = *(const short8*)(HB[ss] + rA1 * 72 + ks * 32 + quad * 8);
                }
            for (int cc = 0; cc < 2; cc++) {
                // FFN1 chunk: 7 n-tiles over 4 waves -> FB bf16 [25][136]
                for (int u = wid; u < 7; u += 4) {
                    int c1 = cc * 112 + u * 16 + nl;
                    const unsigned short* bp = w1t_all + (((size_t)(l * 224 + c1)) << 6) + quad * 8;
                    short8 b0f = *(const short8*)(bp);
                    short8 b1f = *(const short8*)(bp + 32);
                    float bias = b1[l * 224 + c1];
                    #pragma unroll
                    for (int ss = 0; ss < 2; ss++) {
                        f32x4 acc0 = {0, 0, 0, 0}, acc1 = {0, 0, 0, 0};
                        acc0 = __builtin_amdgcn_mfma_f32_16x16x32_bf16(a[ss][0][0], b0f, acc0, 0, 0, 0);
                        acc0 = __builtin_amdgcn_mfma_f32_16x16x32_bf16(a[ss][0][1], b1f, acc0, 0, 0, 0);
                        acc1 = __builtin_amdgcn_mfma_f32_16x16x32_bf16(a[ss][1][0], b0f, acc1, 0, 0, 0);
                        acc1 = __builtin_amdgcn_mfma_f32_16x16x32_bf16(a[ss][1][1], b1f, acc1, 0, 0, 0);
                        unsigned short* FB = UNI[ss];
                        int lc = u * 16 + nl;
                        #pragma unroll
                        for (int r = 0; r < 4; r++) {
                            int row0 = quad * 4 + r;
                            FB[row0 * FSTR + lc] = f2bf_t(gelu_sig(acc0[r] + bias));
                            int row1 = 16 + row0;
                            if (row1 < 25) FB[row1 * FSTR + lc] = f2bf_t(gelu_sig(acc1[r] + bias));
                        }
                    }
                }
                // zero pad cols 112..127 (K-pad for FFN2's 4th k-step)
                if (tid < 200) {
                    int s = tid >> 3, jj = (tid & 7) * 2;
                    *(unsigned int*)(UNI[0] + s * FSTR + 112 + jj) = 0;
                    *(unsigned int*)(UNI[1] + s * FSTR + 112 + jj) = 0;
                }
                __syncthreads();

                // FFN2 chunk: K=128 (4 k-steps); w2t rows 256-wide zero-padded
                {
                    const unsigned short* bp0 = w2t_all + (((size_t)(l * 64 + col)) << 8) + cc * 112 + quad * 8;
                    f32x4 acc0a = {0,0,0,0}, acc1a = {0,0,0,0}, acc0b = {0,0,0,0}, acc1b = {0,0,0,0};
                    #pragma unroll
                    for (int ks = 0; ks < 4; ks++) {
                        short8 bfrag = *(const short8*)(bp0 + ks * 32);
                        const unsigned short* FBa = UNI[0];
                        const unsigned short* FBb = UNI[1];
                        short8 a0a = *(const short8*)(FBa + nl * FSTR + ks * 32 + quad * 8);
                        short8 a1a = *(const short8*)(FBa + rA1 * FSTR + ks * 32 + quad * 8);
                        short8 a0b = *(const short8*)(FBb + nl * FSTR + ks * 32 + quad * 8);
                        short8 a1b = *(const short8*)(FBb + rA1 * FSTR + ks * 32 + quad * 8);
                        acc0a = __builtin_amdgcn_mfma_f32_16x16x32_bf16(a0a, bfrag, acc0a, 0, 0, 0);
                        acc0b = __builtin_amdgcn_mfma_f32_16x16x32_bf16(a0b, bfrag, acc0b, 0, 0, 0);
                        acc1a = __builtin_amdgcn_mfma_f32_16x16x32_bf16(a1a, bfrag, acc1a, 0, 0, 0);
                        acc1b = __builtin_amdgcn_mfma_f32_16x16x32_bf16(a1b, bfrag, acc1b, 0, 0, 0);
                    }
                    if (col < 56) {
                        float bias = (cc == 0) ? b2[l * 56 + col] : 0.f;
                        #pragma unroll
                        for (int r = 0; r < 4; r++) {
                            int row0 = quad * 4 + r;
                            _Float16* x0a = &XSH[0][row0 * 56 + col];
                            _Float16* x0b = &XSH[1][row0 * 56 + col];
                            *x0a = (_Float16)((float)*x0a + acc0a[r] + bias);
                            *x0b = (_Float16)((float)*x0b + acc0b[r] + bias);
                            int row1 = 16 + row0;
                            if (row1 < 25) {
                                _Float16* x1a = &XSH[0][row1 * 56 + col];
                                _Float16* x1b = &XSH[1][row1 * 56 + col];
                                *x1a = (_Float16)((float)*x1a + acc1a[r] + bias);
                                *x1b = (_Float16)((float)*x1b + acc1b[r] + bias);
                            }
                        }
                    }
                }
                __syncthreads();
            }
        }
    }

    // ---- output: both samples ----
    for (int t = tid; t < 80; t += NTH) {
        int ss = t / 40, r = t - ss * 40;
        int s = r >> 3, j = r & 7;
        int bb = b0 + ss;
        if (bb < Btot) out[(bb * 5 + s) * 8 + j] = (float)XSH[ss][s * 56 + 8 + j];
    }
}

extern "C" void kernel_launch(void* const* d_in, const int* in_sizes, int n_in,
                              void* d_out, int out_size, void* d_ws, size_t ws_size,
                              hipStream_t stream) {
    const float* nodes = (const float*)d_in[0];
    const float* edges = (const float*)d_in[1];
    const float* mask  = (const float*)d_in[2];
    const int B = in_sizes[0] / 120;
    const float* W_in = (const float*)d_in[4];
    const float* b_in = (const float*)d_in[5];
    const float* W_gp = (const float*)d_in[6];
    const float* b_gp = (const float*)d_in[7];
    const float* Wq   = (const float*)d_in[8];
    const float* Wk   = (const float*)d_in[9];
    const float* Wv   = (const float*)d_in[10];
    const float* Wo   = (const float*)d_in[11];
    const float* ln1g = (const float*)d_in[12];
    const float* ln1b = (const float*)d_in[13];
    const float* ln2g = (const float*)d_in[14];
    const float* ln2b = (const float*)d_in[15];
    const float* W1   = (const float*)d_in[16];
    const float* b1   = (const float*)d_in[17];
    const float* W2   = (const float*)d_in[18];
    const float* b2   = (const float*)d_in[19];
    float* out = (float*)d_out;
    const int L = in_sizes[8] / 3136;

    unsigned short* ws16 = (unsigned short*)d_ws;
    int prep_total = L * (16384 + 14336 + 16384);
    hipLaunchKernelGGL(prep_weights, dim3((prep_total + NTH - 1) / NTH), dim3(NTH), 0, stream,
                       Wq, Wk, Wv, Wo, W1, W2, ws16, L);

    hipLaunchKernelGGL(nbody_fused, dim3((B + 1) / 2), dim3(NTH), 0, stream,
                       nodes, edges, mask, W_in, b_in, W_gp, b_gp,
                       ln1g, ln1b, ln2g, ln2b, b1, b2, ws16, L, B, out);
}

// Round 20
// 320.431 us; speedup vs baseline: 1.3998x; 1.3998x over previous
//
#include <hip/hip_runtime.h>
#include <math.h>

#define NTH 256
#define QHSTR 64    // Q/K/V f16 stride (halves): head h at col h*8 (7+1 pad)
#define FSTR 136    // FB chunk stride (ushorts): 112 real + 16 zero-pad + 8 unused
#define LOG2E 1.4426950408889634f

typedef __attribute__((ext_vector_type(8))) short short8;
typedef __attribute__((ext_vector_type(4))) float f32x4;
typedef _Float16 half2_t __attribute__((ext_vector_type(2)));

__device__ __forceinline__ half2_t as_h2(unsigned int u) {
    return __builtin_bit_cast(half2_t, u);
}
__device__ __forceinline__ float fast_exp2(float x) {
    float r;
    asm("v_exp_f32 %0, %1" : "=v"(r) : "v"(x));
    return r;
}
__device__ __forceinline__ unsigned short f2bf(float x) {          // RNE (prep only)
    unsigned int u = __float_as_uint(x);
    return (unsigned short)((u + 0x7FFFu + ((u >> 16) & 1u)) >> 16);
}
__device__ __forceinline__ unsigned short f2bf_t(float x) {        // truncate (MFMA inputs only)
    return (unsigned short)(__float_as_uint(x) >> 16);
}

__host__ __device__ constexpr int pc_(int v) { int c = 0; while (v) { c += v & 1; v >>= 1; } return c; }
__host__ __device__ constexpr int gp_sign(int a, int b) {
    int s = 0; int t = a >> 1;
    while (t) { s += pc_(t & b); t >>= 1; }
    return (s & 1) ? -1 : 1;
}
#define BLADE(i) ((int)((0x76534210u >> ((i) * 4)) & 0xF))

__device__ __forceinline__ float gelu_sig(float z) {
    float E = fast_exp2(-2.4554669f * z);
    return z * __builtin_amdgcn_rcpf(1.0f + E);
}

// ---------------- weight prep: bf16, transposed, zero-padded ----------------
// ws layout (ushorts): [0, L*16384) qkvo [(l*4+mat)*64+n]*64+k
//                      [+, L*14336) w1t  [(l*224+n)*64+k]
//                      [+, L*16384) w2t  [(l*64+n)*256+k]  (k<224 real, else 0)
__global__ void prep_weights(const float* __restrict__ Wq, const float* __restrict__ Wk,
                             const float* __restrict__ Wv, const float* __restrict__ Wo,
                             const float* __restrict__ W1, const float* __restrict__ W2,
                             unsigned short* __restrict__ ws, int L)
{
    int idx = blockIdx.x * NTH + threadIdx.x;
    int total1 = L * 16384, total2 = L * 14336, total3 = L * 16384;
    if (idx < total1) {
        int k = idx & 63, n = (idx >> 6) & 63, mat = (idx >> 12) & 3, l = idx >> 14;
        float v = 0.f;
        if (k < 56 && n < 56) {
            const float* W = (mat == 0) ? Wq : (mat == 1) ? Wk : (mat == 2) ? Wv : Wo;
            v = W[l * 3136 + k * 56 + n];
            if (mat == 0) v *= 0.3779644730092272f * LOG2E;  // 1/sqrt(7) and log2e folded
        }
        ws[idx] = f2bf(v);
    } else if (idx < total1 + total2) {
        int t = idx - total1;
        int k = t & 63, n = (t >> 6) % 224, l = t / 14336;
        float v = (k < 56) ? W1[l * 12544 + k * 224 + n] : 0.f;
        ws[idx] = f2bf(v);
    } else if (idx < total1 + total2 + total3) {
        int t = idx - total1 - total2;
        int k = t & 255, n = (t >> 8) & 63, l = t >> 14;
        float v = (k < 224 && n < 56) ? W2[l * 12544 + k * 56 + n] : 0.f;
        ws[idx] = f2bf(v);
    }
}

__global__ __launch_bounds__(NTH, 4) void nbody_fused(
    const float* __restrict__ nodes, const float* __restrict__ edges,
    const float* __restrict__ src_mask,
    const float* __restrict__ W_in, const float* __restrict__ b_in,
    const float* __restrict__ W_gp, const float* __restrict__ b_gp,
    const float* __restrict__ ln1g, const float* __restrict__ ln1b,
    const float* __restrict__ ln2g, const float* __restrict__ ln2b,
    const float* __restrict__ b1, const float* __restrict__ b2,
    const unsigned short* __restrict__ ws, int L, int Btot,
    float* __restrict__ out)
{
    // 5600 + 7200 + 19200 = 32000 B -> 5 blocks/CU (VGPR permitting at bounds 4)
    __shared__ __align__(16) _Float16 XSH[2][1400];           // residual f16 [25][56] (RNE cvt RMW)
    __shared__ __align__(16) unsigned short HB[2][1800];      // h bf16 [25][72], cols56-63 zero
    __shared__ __align__(16) unsigned short UNI[2][4800];     // QKV-f16 [3][25][64] / FB [25][136] / staging

    const int b0 = blockIdx.x * 2, tid = threadIdx.x;
    const int lane = tid & 63, wid = tid >> 6;
    const int nl = lane & 15, quad = lane >> 4;
    const int col = wid * 16 + nl;
    const int pcolh = (col / 7) * 8 + col % 7;
    const int ln_p = lane & 7;
    const int ln_s = wid + 4 * (lane >> 3);                // fused-LN row (valid if <25)
    int rA1 = 16 + nl; if (rA1 > 24) rA1 = 24;             // clamped A-row for tile 1
    const int bbm1 = (b0 + 1 < Btot) ? (b0 + 1) : (Btot - 1);

    // ---- P0: load src (f16) for both samples; zero HB k-pads ----
    for (int t = tid; t < 1200; t += NTH) {
        int ss = t / 600, r0 = t - ss * 600;
        int s = r0 / 24, r = r0 % 24;
        int bb = b0 + ss;
        if (bb < Btot)
            XSH[ss][r0] = (_Float16)((s < 5) ? nodes[bb * 120 + r0] : edges[bb * 480 + (s - 5) * 24 + r]);
    }
    for (int t = tid; t < 400; t += NTH) {
        int ss = t / 200, r0 = t - ss * 200;
        int r = r0 >> 3, c = 56 + (r0 & 7);
        HB[ss][r * 72 + c] = 0;
    }
    __syncthreads();

    // ---- P1: src_mv -> KBs f16 (per sample) ----
    #pragma unroll
    for (int ss = 0; ss < 2; ss++) {
        _Float16* KBs = (_Float16*)UNI[ss];
        for (int t = tid; t < 1400; t += NTH) {
            int s = t / 56, rem = t % 56, n = rem >> 3, i = rem & 7;
            int g = __popc(BLADE(i));
            float acc = (i == 0) ? b_in[n] : 0.0f;
            #pragma unroll
            for (int m = 0; m < 3; m++)
                acc += (float)XSH[ss][s * 24 + m * 8 + i] * W_in[n * 12 + m * 4 + g];
            KBs[s * 56 + rem] = (_Float16)acc;
        }
    }
    __syncthreads();

    // ---- P2: geometric product -> VBs f16 ----
    #pragma unroll
    for (int ss = 0; ss < 2; ss++) {
        _Float16* KBs = (_Float16*)UNI[ss];
        _Float16* VBs = KBs + 1400;
        for (int t = tid; t < 175; t += NTH) {
            int s = t / 7, n = t % 7;
            float m8[8], g8[8];
            #pragma unroll
            for (int i = 0; i < 8; i++) { m8[i] = (float)KBs[s * 56 + n * 8 + i]; g8[i] = 0.0f; }
            #pragma unroll
            for (int ai = 0; ai < 8; ai++) {
                const int a = BLADE(ai);
                #pragma unroll
                for (int bi = 0; bi < 8; bi++) {
                    const int bb = BLADE(bi);
                    const int j = BLADE(a ^ bb);
                    const int sg = gp_sign(a, bb);
                    g8[j] += (sg > 0) ? (m8[ai] * m8[bi]) : (-m8[ai] * m8[bi]);
                }
            }
            #pragma unroll
            for (int j = 0; j < 8; j++) VBs[s * 56 + n * 8 + j] = (_Float16)g8[j];
        }
    }
    __syncthreads();

    // ---- P3: src2 -> XSH f16 ----
    #pragma unroll
    for (int ss = 0; ss < 2; ss++) {
        const _Float16* KBs = (const _Float16*)UNI[ss];
        const _Float16* VBs = KBs + 1400;
        for (int t = tid; t < 1400; t += NTH) {
            int s = t / 56, rem = t % 56, n = rem >> 3, i = rem & 7;
            int g = __popc(BLADE(i));
            float acc = (i == 0) ? b_gp[n] : 0.0f;
            #pragma unroll
            for (int m = 0; m < 7; m++)
                acc += (float)KBs[s * 56 + m * 8 + i] * W_gp[n * 56 + m * 4 + g];
            #pragma unroll
            for (int m = 0; m < 7; m++)
                acc += (float)VBs[s * 56 + m * 8 + i] * W_gp[n * 56 + (7 + m) * 4 + g];
            XSH[ss][s * 56 + rem] = (_Float16)acc;
        }
    }
    __syncthreads();

    const unsigned short* w1t_all = ws + (size_t)L * 16384;
    const unsigned short* w2t_all = w1t_all + (size_t)L * 14336;

    for (int l = 0; l < L; l++) {
        const float* g1 = ln1g + l * 56; const float* e1 = ln1b + l * 56;
        const float* g2 = ln2g + l * 56; const float* e2 = ln2b + l * 56;

        // ---- fused LN1 (both samples) + zero Q/K head-pads ----
        if (tid < 200) {
            int s = tid >> 3, hh = tid & 7;
            #pragma unroll
            for (int ss = 0; ss < 2; ss++) {
                _Float16* QH = (_Float16*)UNI[ss];
                _Float16* KH = QH + 25 * QHSTR;
                QH[s * QHSTR + hh * 8 + 7] = (_Float16)0.f;
                KH[s * QHSTR + hh * 8 + 7] = (_Float16)0.f;
            }
        }
        #pragma unroll
        for (int ss = 0; ss < 2; ss++) {
            float x[7]; float sum = 0.f, sq = 0.f;
            if (ln_s < 25) {
                const _Float16* xp = XSH[ss] + ln_s * 56 + ln_p * 7;
                #pragma unroll
                for (int j = 0; j < 7; j++) { x[j] = (float)xp[j]; sum += x[j]; sq += x[j] * x[j]; }
            }
            #pragma unroll
            for (int off = 1; off < 8; off <<= 1) {
                sum += __shfl_xor(sum, off, 64);
                sq  += __shfl_xor(sq,  off, 64);
            }
            if (ln_s < 25) {
                float mean = sum * (1.0f / 56.0f);
                float rs = __builtin_amdgcn_rsqf(sq * (1.0f / 56.0f) - mean * mean + 1e-5f);
                unsigned short* hp = HB[ss] + ln_s * 72 + ln_p * 7;
                #pragma unroll
                for (int j = 0; j < 7; j++) {
                    int d = ln_p * 7 + j;
                    hp[j] = f2bf_t((x[j] - mean) * rs * g1[d] + e1[d]);
                }
            }
        }
        __syncthreads();

        // ---- QKV via MFMA: shared B-frags, dual-sample A (clamped A rows) ----
        {
            short8 a[2][2][2];   // [ss][mt][ks]
            #pragma unroll
            for (int ss = 0; ss < 2; ss++)
                #pragma unroll
                for (int ks = 0; ks < 2; ks++) {
                    a[ss][0][ks] = *(const short8*)(HB[ss] + nl * 72 + ks * 32 + quad * 8);
                    a[ss][1][ks] = *(const short8*)(HB[ss] + rA1 * 72 + ks * 32 + quad * 8);
                }
            #pragma unroll
            for (int mat = 0; mat < 3; mat++) {
                const unsigned short* bp = ws + (((size_t)(l * 4 + mat)) << 12) + (((size_t)col) << 6) + quad * 8;
                short8 b0f = *(const short8*)(bp);
                short8 b1f = *(const short8*)(bp + 32);
                #pragma unroll
                for (int ss = 0; ss < 2; ss++) {
                    f32x4 acc0 = {0, 0, 0, 0}, acc1 = {0, 0, 0, 0};
                    acc0 = __builtin_amdgcn_mfma_f32_16x16x32_bf16(a[ss][0][0], b0f, acc0, 0, 0, 0);
                    acc0 = __builtin_amdgcn_mfma_f32_16x16x32_bf16(a[ss][0][1], b1f, acc0, 0, 0, 0);
                    acc1 = __builtin_amdgcn_mfma_f32_16x16x32_bf16(a[ss][1][0], b0f, acc1, 0, 0, 0);
                    acc1 = __builtin_amdgcn_mfma_f32_16x16x32_bf16(a[ss][1][1], b1f, acc1, 0, 0, 0);
                    _Float16* dst = (_Float16*)UNI[ss] + mat * 25 * QHSTR;
                    if (col < 56) {
                        #pragma unroll
                        for (int r = 0; r < 4; r++) {
                            int row0 = quad * 4 + r;
                            dst[row0 * QHSTR + pcolh] = (_Float16)acc0[r];
                            int row1 = 16 + row0;
                            if (row1 < 25) dst[row1 * QHSTR + pcolh] = (_Float16)acc1[r];
                        }
                    }
                }
            }
        }
        __syncthreads();

        // ---- attention: dual-sample interleaved; mask from global (L2-hot) ----
        if (tid < 200) {
            int s = tid >> 3, hh = tid & 7;
            const _Float16* QHa = (const _Float16*)UNI[0];
            const _Float16* QHb = (const _Float16*)UNI[1];
            const _Float16* KHa = QHa + 25 * QHSTR, * VHa = KHa + 25 * QHSTR;
            const _Float16* KHb = QHb + 25 * QHSTR, * VHb = KHb + 25 * QHSTR;
            const float* mka = src_mask + (size_t)b0 * 625 + s * 25;
            const float* mkb = src_mask + (size_t)bbm1 * 625 + s * 25;
            uint4 Qa = *(const uint4*)(QHa + s * QHSTR + hh * 8);
            uint4 Qb = *(const uint4*)(QHb + s * QHSTR + hh * 8);
            half2_t qa0 = as_h2(Qa.x), qa1 = as_h2(Qa.y), qa2 = as_h2(Qa.z), qa3 = as_h2(Qa.w);
            half2_t qb0 = as_h2(Qb.x), qb1 = as_h2(Qb.y), qb2 = as_h2(Qb.z), qb3 = as_h2(Qb.w);
            float lsa = 0.f, lsb = 0.f;
            half2_t aa0 = {0,0}, aa1 = {0,0}, aa2 = {0,0}, aa3 = {0,0};
            half2_t ab0 = {0,0}, ab1 = {0,0}, ab2 = {0,0}, ab3 = {0,0};
            for (int kk = 0; kk < 25; kk++) {
                uint4 Ka = *(const uint4*)(KHa + kk * QHSTR + hh * 8);
                uint4 Kb = *(const uint4*)(KHb + kk * QHSTR + hh * 8);
                float da = mka[kk] * LOG2E;
                float db = mkb[kk] * LOG2E;
                da = __builtin_amdgcn_fdot2(qa3, as_h2(Ka.w), da, false);
                db = __builtin_amdgcn_fdot2(qb3, as_h2(Kb.w), db, false);
                da = __builtin_amdgcn_fdot2(qa2, as_h2(Ka.z), da, false);
                db = __builtin_amdgcn_fdot2(qb2, as_h2(Kb.z), db, false);
                da = __builtin_amdgcn_fdot2(qa1, as_h2(Ka.y), da, false);
                db = __builtin_amdgcn_fdot2(qb1, as_h2(Kb.y), db, false);
                da = __builtin_amdgcn_fdot2(qa0, as_h2(Ka.x), da, false);
                db = __builtin_amdgcn_fdot2(qb0, as_h2(Kb.x), db, false);
                float pa = fast_exp2(da);
                float pb = fast_exp2(db);
                lsa += pa; lsb += pb;
                uint4 Va = *(const uint4*)(VHa + kk * QHSTR + hh * 8);
                uint4 Vb = *(const uint4*)(VHb + kk * QHSTR + hh * 8);
                _Float16 pha = (_Float16)pa, phb = (_Float16)pb;
                half2_t p2a = {pha, pha}, p2b = {phb, phb};
                aa0 += p2a * as_h2(Va.x); aa1 += p2a * as_h2(Va.y);
                aa2 += p2a * as_h2(Va.z); aa3 += p2a * as_h2(Va.w);
                ab0 += p2b * as_h2(Vb.x); ab1 += p2b * as_h2(Vb.y);
                ab2 += p2b * as_h2(Vb.z); ab3 += p2b * as_h2(Vb.w);
            }
            float inva = __builtin_amdgcn_rcpf(lsa);
            float invb = __builtin_amdgcn_rcpf(lsb);
            unsigned short* opa = HB[0] + s * 72 + hh * 7;
            unsigned short* opb = HB[1] + s * 72 + hh * 7;
            opa[0] = f2bf_t((float)aa0.x * inva); opa[1] = f2bf_t((float)aa0.y * inva);
            opa[2] = f2bf_t((float)aa1.x * inva); opa[3] = f2bf_t((float)aa1.y * inva);
            opa[4] = f2bf_t((float)aa2.x * inva); opa[5] = f2bf_t((float)aa2.y * inva);
            opa[6] = f2bf_t((float)aa3.x * inva);
            opb[0] = f2bf_t((float)ab0.x * invb); opb[1] = f2bf_t((float)ab0.y * invb);
            opb[2] = f2bf_t((float)ab1.x * invb); opb[3] = f2bf_t((float)ab1.y * invb);
            opb[4] = f2bf_t((float)ab2.x * invb); opb[5] = f2bf_t((float)ab2.y * invb);
            opb[6] = f2bf_t((float)ab3.x * invb);
        }
        __syncthreads();

        // ---- x += o @ Wo (shared B-frags, clamped A rows; f16 RNE RMW) ----
        {
            short8 a[2][2][2];
            #pragma unroll
            for (int ss = 0; ss < 2; ss++)
                #pragma unroll
                for (int ks = 0; ks < 2; ks++) {
                    a[ss][0][ks] = *(const short8*)(HB[ss] + nl * 72 + ks * 32 + quad * 8);
                    a[ss][1][ks] = *(const short8*)(HB[ss] + rA1 * 72 + ks * 32 + quad * 8);
                }
            const unsigned short* bp = ws + (((size_t)(l * 4 + 3)) << 12) + (((size_t)col) << 6) + quad * 8;
            short8 b0f = *(const short8*)(bp);
            short8 b1f = *(const short8*)(bp + 32);
            #pragma unroll
            for (int ss = 0; ss < 2; ss++) {
                f32x4 acc0 = {0, 0, 0, 0}, acc1 = {0, 0, 0, 0};
                acc0 = __builtin_amdgcn_mfma_f32_16x16x32_bf16(a[ss][0][0], b0f, acc0, 0, 0, 0);
                acc0 = __builtin_amdgcn_mfma_f32_16x16x32_bf16(a[ss][0][1], b1f, acc0, 0, 0, 0);
                acc1 = __builtin_amdgcn_mfma_f32_16x16x32_bf16(a[ss][1][0], b0f, acc1, 0, 0, 0);
                acc1 = __builtin_amdgcn_mfma_f32_16x16x32_bf16(a[ss][1][1], b1f, acc1, 0, 0, 0);
                if (col < 56) {
                    #pragma unroll
                    for (int r = 0; r < 4; r++) {
                        int row0 = quad * 4 + r;
                        _Float16* xp0 = &XSH[ss][row0 * 56 + col];
                        *xp0 = (_Float16)((float)*xp0 + acc0[r]);
                        int row1 = 16 + row0;
                        if (row1 < 25) {
                            _Float16* xp1 = &XSH[ss][row1 * 56 + col];
                            *xp1 = (_Float16)((float)*xp1 + acc1[r]);
                        }
                    }
                }
            }
        }
        __syncthreads();

        // ---- fused LN2 ----
        #pragma unroll
        for (int ss = 0; ss < 2; ss++) {
            float x[7]; float sum = 0.f, sq = 0.f;
            if (ln_s < 25) {
                const _Float16* xp = XSH[ss] + ln_s * 56 + ln_p * 7;
                #pragma unroll
                for (int j = 0; j < 7; j++) { x[j] = (float)xp[j]; sum += x[j]; sq += x[j] * x[j]; }
            }
            #pragma unroll
            for (int off = 1; off < 8; off <<= 1) {
                sum += __shfl_xor(sum, off, 64);
                sq  += __shfl_xor(sq,  off, 64);
            }
            if (ln_s < 25) {
                float mean = sum * (1.0f / 56.0f);
                float rs = __builtin_amdgcn_rsqf(sq * (1.0f / 56.0f) - mean * mean + 1e-5f);
                unsigned short* hp = HB[ss] + ln_s * 72 + ln_p * 7;
                #pragma unroll
                for (int j = 0; j < 7; j++) {
                    int d = ln_p * 7 + j;
                    hp[j] = f2bf_t((x[j] - mean) * rs * g2[d] + e2[d]);
                }
            }
        }
        __syncthreads();

        // ---- FFN in two 112-col chunks ----
        {
            short8 a[2][2][2];
            #pragma unroll
            for (int ss = 0; ss < 2; ss++)
                #pragma unroll
                for (int ks = 0; ks < 2; ks++) {
                    a[ss][0][ks] = *(const short8*)(HB[ss] + nl * 72 + ks * 32 + quad * 8);
                    a[ss][1][ks] = *(const short8*)(HB[ss] + rA1 * 72 + ks * 32 + quad * 8);
                }
            for (int cc = 0; cc < 2; cc++) {
                // FFN1 chunk: 7 n-tiles over 4 waves -> FB bf16 [25][136]
                for (int u = wid; u < 7; u += 4) {
                    int c1 = cc * 112 + u * 16 + nl;
                    const unsigned short* bp = w1t_all + (((size_t)(l * 224 + c1)) << 6) + quad * 8;
                    short8 b0f = *(const short8*)(bp);
                    short8 b1f = *(const short8*)(bp + 32);
                    float bias = b1[l * 224 + c1];
                    #pragma unroll
                    for (int ss = 0; ss < 2; ss++) {
                        f32x4 acc0 = {0, 0, 0, 0}, acc1 = {0, 0, 0, 0};
                        acc0 = __builtin_amdgcn_mfma_f32_16x16x32_bf16(a[ss][0][0], b0f, acc0, 0, 0, 0);
                        acc0 = __builtin_amdgcn_mfma_f32_16x16x32_bf16(a[ss][0][1], b1f, acc0, 0, 0, 0);
                        acc1 = __builtin_amdgcn_mfma_f32_16x16x32_bf16(a[ss][1][0], b0f, acc1, 0, 0, 0);
                        acc1 = __builtin_amdgcn_mfma_f32_16x16x32_bf16(a[ss][1][1], b1f, acc1, 0, 0, 0);
                        unsigned short* FB = UNI[ss];
                        int lc = u * 16 + nl;
                        #pragma unroll
                        for (int r = 0; r < 4; r++) {
                            int row0 = quad * 4 + r;
                            FB[row0 * FSTR + lc] = f2bf_t(gelu_sig(acc0[r] + bias));
                            int row1 = 16 + row0;
                            if (row1 < 25) FB[row1 * FSTR + lc] = f2bf_t(gelu_sig(acc1[r] + bias));
                        }
                    }
                }
                // zero pad cols 112..127 (K-pad for FFN2's 4th k-step)
                if (tid < 200) {
                    int s = tid >> 3, jj = (tid & 7) * 2;
                    *(unsigned int*)(UNI[0] + s * FSTR + 112 + jj) = 0;
                    *(unsigned int*)(UNI[1] + s * FSTR + 112 + jj) = 0;
                }
                __syncthreads();

                // FFN2 chunk: K=128 (4 k-steps); w2t rows 256-wide zero-padded
                {
                    const unsigned short* bp0 = w2t_all + (((size_t)(l * 64 + col)) << 8) + cc * 112 + quad * 8;
                    f32x4 acc0a = {0,0,0,0}, acc1a = {0,0,0,0}, acc0b = {0,0,0,0}, acc1b = {0,0,0,0};
                    #pragma unroll
                    for (int ks = 0; ks < 4; ks++) {
                        short8 bfrag = *(const short8*)(bp0 + ks * 32);
                        const unsigned short* FBa = UNI[0];
                        const unsigned short* FBb = UNI[1];
                        short8 a0a = *(const short8*)(FBa + nl * FSTR + ks * 32 + quad * 8);
                        short8 a1a = *(const short8*)(FBa + rA1 * FSTR + ks * 32 + quad * 8);
                        short8 a0b = *(const short8*)(FBb + nl * FSTR + ks * 32 + quad * 8);
                        short8 a1b = *(const short8*)(FBb + rA1 * FSTR + ks * 32 + quad * 8);
                        acc0a = __builtin_amdgcn_mfma_f32_16x16x32_bf16(a0a, bfrag, acc0a, 0, 0, 0);
                        acc0b = __builtin_amdgcn_mfma_f32_16x16x32_bf16(a0b, bfrag, acc0b, 0, 0, 0);
                        acc1a = __builtin_amdgcn_mfma_f32_16x16x32_bf16(a1a, bfrag, acc1a, 0, 0, 0);
                        acc1b = __builtin_amdgcn_mfma_f32_16x16x32_bf16(a1b, bfrag, acc1b, 0, 0, 0);
                    }
                    if (col < 56) {
                        float bias = (cc == 0) ? b2[l * 56 + col] : 0.f;
                        #pragma unroll
                        for (int r = 0; r < 4; r++) {
                            int row0 = quad * 4 + r;
                            _Float16* x0a = &XSH[0][row0 * 56 + col];
                            _Float16* x0b = &XSH[1][row0 * 56 + col];
                            *x0a = (_Float16)((float)*x0a + acc0a[r] + bias);
                            *x0b = (_Float16)((float)*x0b + acc0b[r] + bias);
                            int row1 = 16 + row0;
                            if (row1 < 25) {
                                _Float16* x1a = &XSH[0][row1 * 56 + col];
                                _Float16* x1b = &XSH[1][row1 * 56 + col];
                                *x1a = (_Float16)((float)*x1a + acc1a[r] + bias);
                                *x1b = (_Float16)((float)*x1b + acc1b[r] + bias);
                            }
                        }
                    }
                }
                __syncthreads();
            }
        }
    }

    // ---- output: both samples ----
    for (int t = tid; t < 80; t += NTH) {
        int ss = t / 40, r = t - ss * 40;
        int s = r >> 3, j = r & 7;
        int bb = b0 + ss;
        if (bb < Btot) out[(bb * 5 + s) * 8 + j] = (float)XSH[ss][s * 56 + 8 + j];
    }
}

extern "C" void kernel_launch(void* const* d_in, const int* in_sizes, int n_in,
                              void* d_out, int out_size, void* d_ws, size_t ws_size,
                              hipStream_t stream) {
    const float* nodes = (const float*)d_in[0];
    const float* edges = (const float*)d_in[1];
    const float* mask  = (const float*)d_in[2];
    const int B = in_sizes[0] / 120;
    const float* W_in = (const float*)d_in[4];
    const float* b_in = (const float*)d_in[5];
    const float* W_gp = (const float*)d_in[6];
    const float* b_gp = (const float*)d_in[7];
    const float* Wq   = (const float*)d_in[8];
    const float* Wk   = (const float*)d_in[9];
    const float* Wv   = (const float*)d_in[10];
    const float* Wo   = (const float*)d_in[11];
    const float* ln1g = (const float*)d_in[12];
    const float* ln1b = (const float*)d_in[13];
    const float* ln2g = (const float*)d_in[14];
    const float* ln2b = (const float*)d_in[15];
    const float* W1   = (const float*)d_in[16];
    const float* b1   = (const float*)d_in[17];
    const float* W2   = (const float*)d_in[18];
    const float* b2   = (const float*)d_in[19];
    float* out = (float*)d_out;
    const int L = in_sizes[8] / 3136;

    unsigned short* ws16 = (unsigned short*)d_ws;
    int prep_total = L * (16384 + 14336 + 16384);
    hipLaunchKernelGGL(prep_weights, dim3((prep_total + NTH - 1) / NTH), dim3(NTH), 0, stream,
                       Wq, Wk, Wv, Wo, W1, W2, ws16, L);

    hipLaunchKernelGGL(nbody_fused, dim3((B + 1) / 2), dim3(NTH), 0, stream,
                       nodes, edges, mask, W_in, b_in, W_gp, b_gp,
                       ln1g, ln1b, ln2g, ln2b, b1, b2, ws16, L, B, out);
}

// Round 21
// 293.152 us; speedup vs baseline: 1.5300x; 1.0931x over previous
//
#include <hip/hip_runtime.h>
#include <math.h>

#define NTH 256
#define XSTR 56     // XS stride (floats)
#define QHSTR 72    // Q/K/V f16 stride (halves): head h at col h*8 (7+1 pad)
#define FSTR 224    // FB stride (ushorts); 25 rows exact (5600 shorts)
#define LOG2E 1.4426950408889634f

typedef __attribute__((ext_vector_type(8))) short short8;
typedef __attribute__((ext_vector_type(4))) float f32x4;
typedef _Float16 half2_t __attribute__((ext_vector_type(2)));

__device__ __forceinline__ half2_t as_h2(unsigned int u) {
    return __builtin_bit_cast(half2_t, u);
}
__device__ __forceinline__ float fast_exp2(float x) {
    float r;
    asm("v_exp_f32 %0, %1" : "=v"(r) : "v"(x));
    return r;
}
__device__ __forceinline__ unsigned short f2bf(float x) {          // RNE (prep only)
    unsigned int u = __float_as_uint(x);
    return (unsigned short)((u + 0x7FFFu + ((u >> 16) & 1u)) >> 16);
}
__device__ __forceinline__ unsigned short f2bf_t(float x) {        // truncate
    return (unsigned short)(__float_as_uint(x) >> 16);
}

__host__ __device__ constexpr int pc_(int v) { int c = 0; while (v) { c += v & 1; v >>= 1; } return c; }
__host__ __device__ constexpr int gp_sign(int a, int b) {
    int s = 0; int t = a >> 1;
    while (t) { s += pc_(t & b); t >>= 1; }
    return (s & 1) ? -1 : 1;
}
#define BLADE(i) ((int)((0x76534210u >> ((i) * 4)) & 0xF))

__device__ __forceinline__ float gelu_sig(float z) {
    float E = fast_exp2(-2.4554669f * z);
    return z * __builtin_amdgcn_rcpf(1.0f + E);
}

// ---------------- weight prep: bf16, transposed (WT[n][k]), zero-padded ----------------
__global__ void prep_weights(const float* __restrict__ Wq, const float* __restrict__ Wk,
                             const float* __restrict__ Wv, const float* __restrict__ Wo,
                             const float* __restrict__ W1, const float* __restrict__ W2,
                             unsigned short* __restrict__ ws, int L)
{
    int idx = blockIdx.x * NTH + threadIdx.x;
    int total1 = L * 16384, total2 = L * 14336, total3 = L * 14336;
    if (idx < total1) {
        int k = idx & 63, n = (idx >> 6) & 63, mat = (idx >> 12) & 3, l = idx >> 14;
        float v = 0.f;
        if (k < 56 && n < 56) {
            const float* W = (mat == 0) ? Wq : (mat == 1) ? Wk : (mat == 2) ? Wv : Wo;
            v = W[l * 3136 + k * 56 + n];
            if (mat == 0) v *= 0.3779644730092272f * LOG2E;  // 1/sqrt(7) and log2e folded
        }
        ws[idx] = f2bf(v);
    } else if (idx < total1 + total2) {
        int t = idx - total1;
        int k = t & 63, n = (t >> 6) % 224, l = t / 14336;
        float v = (k < 56) ? W1[l * 12544 + k * 224 + n] : 0.f;
        ws[idx] = f2bf(v);
    } else if (idx < total1 + total2 + total3) {
        int t = idx - total1 - total2;
        int k = t % 224, n = (t / 224) & 63, l = t / 14336;
        float v = (n < 56) ? W2[l * 12544 + k * 56 + n] : 0.f;
        ws[idx] = f2bf(v);
    }
}

__global__ __launch_bounds__(NTH, 4) void nbody_fused(
    const float* __restrict__ nodes, const float* __restrict__ edges,
    const float* __restrict__ src_mask,
    const float* __restrict__ W_in, const float* __restrict__ b_in,
    const float* __restrict__ W_gp, const float* __restrict__ b_gp,
    const float* __restrict__ ln1g, const float* __restrict__ ln1b,
    const float* __restrict__ ln2g, const float* __restrict__ ln2b,
    const float* __restrict__ b1, const float* __restrict__ b2,
    const unsigned short* __restrict__ ws, int L, int Btot,
    float* __restrict__ out)
{
    // 11200 + 7200 + 22400 = 40800 B -> rounds to 40960 = 160KiB/4 -> 4 blocks/CU
    __shared__ __align__(16) float XS[2][25 * XSTR];          // residual fp32
    __shared__ __align__(16) unsigned short HB[2][1800];      // h bf16 [25][72], cols56-63 zero
    __shared__ __align__(16) unsigned short UNI[2][5600];     // QKV-f16 / FB / prologue staging

    const int b0 = blockIdx.x * 2, tid = threadIdx.x;
    const int lane = tid & 63, wid = tid >> 6;
    const int nl = lane & 15, quad = lane >> 4;
    const int col = wid * 16 + nl;
    const int pcolh = (col / 7) * 8 + col % 7;
    const int ln_g = lane >> 3, ln_p = lane & 7;
    const int ln_s = wid + 4 * ln_g;                       // fused-LN row (valid if <25)
    int rA1 = 16 + nl; if (rA1 > 24) rA1 = 24;             // clamped A-row for tile 1
    const int bbm1 = (b0 + 1 < Btot) ? (b0 + 1) : (Btot - 1);

    // ---- P0: load src for both samples; zero HB k-pads ----
    for (int t = tid; t < 1200; t += NTH) {
        int ss = t / 600, r0 = t - ss * 600;
        int s = r0 / 24, r = r0 % 24;
        int bb = b0 + ss;
        if (bb < Btot)
            XS[ss][r0] = (s < 5) ? nodes[bb * 120 + r0] : edges[bb * 480 + (s - 5) * 24 + r];
    }
    for (int t = tid; t < 400; t += NTH) {
        int ss = t / 200, r0 = t - ss * 200;
        int r = r0 >> 3, c = 56 + (r0 & 7);
        HB[ss][r * 72 + c] = 0;
    }
    __syncthreads();

    // ---- P1: src_mv -> KBs (per sample) ----
    #pragma unroll
    for (int ss = 0; ss < 2; ss++) {
        const float* SRCF = XS[ss];
        float* KBs = (float*)UNI[ss];
        for (int t = tid; t < 1400; t += NTH) {
            int s = t / 56, rem = t % 56, n = rem >> 3, i = rem & 7;
            int g = __popc(BLADE(i));
            float acc = (i == 0) ? b_in[n] : 0.0f;
            #pragma unroll
            for (int m = 0; m < 3; m++)
                acc += SRCF[s * 24 + m * 8 + i] * W_in[n * 12 + m * 4 + g];
            KBs[s * 56 + rem] = acc;
        }
    }
    __syncthreads();

    // ---- P2: geometric product -> VBs ----
    #pragma unroll
    for (int ss = 0; ss < 2; ss++) {
        float* KBs = (float*)UNI[ss];
        float* VBs = KBs + 1400;
        for (int t = tid; t < 175; t += NTH) {
            int s = t / 7, n = t % 7;
            float m8[8], g8[8];
            #pragma unroll
            for (int i = 0; i < 8; i++) { m8[i] = KBs[s * 56 + n * 8 + i]; g8[i] = 0.0f; }
            #pragma unroll
            for (int ai = 0; ai < 8; ai++) {
                const int a = BLADE(ai);
                #pragma unroll
                for (int bi = 0; bi < 8; bi++) {
                    const int bb = BLADE(bi);
                    const int j = BLADE(a ^ bb);
                    const int sg = gp_sign(a, bb);
                    g8[j] += (sg > 0) ? (m8[ai] * m8[bi]) : (-m8[ai] * m8[bi]);
                }
            }
            #pragma unroll
            for (int j = 0; j < 8; j++) VBs[s * 56 + n * 8 + j] = g8[j];
        }
    }
    __syncthreads();

    // ---- P3: src2 -> XS ----
    #pragma unroll
    for (int ss = 0; ss < 2; ss++) {
        const float* KBs = (const float*)UNI[ss];
        const float* VBs = KBs + 1400;
        for (int t = tid; t < 1400; t += NTH) {
            int s = t / 56, rem = t % 56, n = rem >> 3, i = rem & 7;
            int g = __popc(BLADE(i));
            float acc = (i == 0) ? b_gp[n] : 0.0f;
            #pragma unroll
            for (int m = 0; m < 7; m++)
                acc += KBs[s * 56 + m * 8 + i] * W_gp[n * 56 + m * 4 + g];
            #pragma unroll
            for (int m = 0; m < 7; m++)
                acc += VBs[s * 56 + m * 8 + i] * W_gp[n * 56 + (7 + m) * 4 + g];
            XS[ss][s * XSTR + rem] = acc;
        }
    }
    __syncthreads();

    const unsigned short* w1t_all = ws + (size_t)L * 16384;
    const unsigned short* w2t_all = w1t_all + (size_t)L * 14336;

    for (int l = 0; l < L; l++) {
        const float* g1 = ln1g + l * 56; const float* e1 = ln1b + l * 56;
        const float* g2 = ln2g + l * 56; const float* e2 = ln2b + l * 56;

        // ---- fused LN1 (both samples) + zero Q/K head-pads ----
        if (tid < 200) {
            int s = tid >> 3, hh = tid & 7;
            #pragma unroll
            for (int ss = 0; ss < 2; ss++) {
                _Float16* QH = (_Float16*)UNI[ss];
                _Float16* KH = QH + 25 * QHSTR;
                QH[s * QHSTR + hh * 8 + 7] = (_Float16)0.f;
                KH[s * QHSTR + hh * 8 + 7] = (_Float16)0.f;
            }
        }
        #pragma unroll
        for (int ss = 0; ss < 2; ss++) {
            float x[7]; float sum = 0.f, sq = 0.f;
            if (ln_s < 25) {
                const float* xp = XS[ss] + ln_s * XSTR + ln_p * 7;
                #pragma unroll
                for (int j = 0; j < 7; j++) { x[j] = xp[j]; sum += x[j]; sq += x[j] * x[j]; }
            }
            #pragma unroll
            for (int off = 1; off < 8; off <<= 1) {
                sum += __shfl_xor(sum, off, 64);
                sq  += __shfl_xor(sq,  off, 64);
            }
            if (ln_s < 25) {
                float mean = sum * (1.0f / 56.0f);
                float rs = __builtin_amdgcn_rsqf(sq * (1.0f / 56.0f) - mean * mean + 1e-5f);
                unsigned short* hp = HB[ss] + ln_s * 72 + ln_p * 7;
                #pragma unroll
                for (int j = 0; j < 7; j++) {
                    int d = ln_p * 7 + j;
                    hp[j] = f2bf_t((x[j] - mean) * rs * g1[d] + e1[d]);
                }
            }
        }
        __syncthreads();

        // ---- QKV via MFMA: shared B-frags, dual-sample A (clamped A rows) ----
        {
            short8 a[2][2][2];   // [ss][mt][ks]
            #pragma unroll
            for (int ss = 0; ss < 2; ss++)
                #pragma unroll
                for (int ks = 0; ks < 2; ks++) {
                    a[ss][0][ks] = *(const short8*)(HB[ss] + nl * 72 + ks * 32 + quad * 8);
                    a[ss][1][ks] = *(const short8*)(HB[ss] + rA1 * 72 + ks * 32 + quad * 8);
                }
            #pragma unroll
            for (int mat = 0; mat < 3; mat++) {
                const unsigned short* bp = ws + (((size_t)(l * 4 + mat)) << 12) + (((size_t)col) << 6) + quad * 8;
                short8 b0f = *(const short8*)(bp);
                short8 b1f = *(const short8*)(bp + 32);
                #pragma unroll
                for (int ss = 0; ss < 2; ss++) {
                    f32x4 acc0 = {0, 0, 0, 0}, acc1 = {0, 0, 0, 0};
                    acc0 = __builtin_amdgcn_mfma_f32_16x16x32_bf16(a[ss][0][0], b0f, acc0, 0, 0, 0);
                    acc0 = __builtin_amdgcn_mfma_f32_16x16x32_bf16(a[ss][0][1], b1f, acc0, 0, 0, 0);
                    acc1 = __builtin_amdgcn_mfma_f32_16x16x32_bf16(a[ss][1][0], b0f, acc1, 0, 0, 0);
                    acc1 = __builtin_amdgcn_mfma_f32_16x16x32_bf16(a[ss][1][1], b1f, acc1, 0, 0, 0);
                    _Float16* dst = (_Float16*)UNI[ss] + mat * 25 * QHSTR;
                    if (col < 56) {
                        #pragma unroll
                        for (int r = 0; r < 4; r++) {
                            int row0 = quad * 4 + r;
                            dst[row0 * QHSTR + pcolh] = (_Float16)acc0[r];
                            int row1 = 16 + row0;
                            if (row1 < 25) dst[row1 * QHSTR + pcolh] = (_Float16)acc1[r];
                        }
                    }
                }
            }
        }
        __syncthreads();

        // ---- attention: dual-sample interleaved; mask read from global (L2-hot) ----
        if (tid < 200) {
            int s = tid >> 3, hh = tid & 7;
            const _Float16* QHa = (const _Float16*)UNI[0];
            const _Float16* QHb = (const _Float16*)UNI[1];
            const _Float16* KHa = QHa + 25 * QHSTR, * VHa = KHa + 25 * QHSTR;
            const _Float16* KHb = QHb + 25 * QHSTR, * VHb = KHb + 25 * QHSTR;
            const float* mka = src_mask + (size_t)b0 * 625 + s * 25;
            const float* mkb = src_mask + (size_t)bbm1 * 625 + s * 25;
            uint4 Qa = *(const uint4*)(QHa + s * QHSTR + hh * 8);
            uint4 Qb = *(const uint4*)(QHb + s * QHSTR + hh * 8);
            half2_t qa0 = as_h2(Qa.x), qa1 = as_h2(Qa.y), qa2 = as_h2(Qa.z), qa3 = as_h2(Qa.w);
            half2_t qb0 = as_h2(Qb.x), qb1 = as_h2(Qb.y), qb2 = as_h2(Qb.z), qb3 = as_h2(Qb.w);
            float lsa = 0.f, lsb = 0.f;
            half2_t aa0 = {0,0}, aa1 = {0,0}, aa2 = {0,0}, aa3 = {0,0};
            half2_t ab0 = {0,0}, ab1 = {0,0}, ab2 = {0,0}, ab3 = {0,0};
            for (int kk = 0; kk < 25; kk++) {
                uint4 Ka = *(const uint4*)(KHa + kk * QHSTR + hh * 8);
                uint4 Kb = *(const uint4*)(KHb + kk * QHSTR + hh * 8);
                float da = mka[kk] * LOG2E;
                float db = mkb[kk] * LOG2E;
                da = __builtin_amdgcn_fdot2(qa3, as_h2(Ka.w), da, false);
                db = __builtin_amdgcn_fdot2(qb3, as_h2(Kb.w), db, false);
                da = __builtin_amdgcn_fdot2(qa2, as_h2(Ka.z), da, false);
                db = __builtin_amdgcn_fdot2(qb2, as_h2(Kb.z), db, false);
                da = __builtin_amdgcn_fdot2(qa1, as_h2(Ka.y), da, false);
                db = __builtin_amdgcn_fdot2(qb1, as_h2(Kb.y), db, false);
                da = __builtin_amdgcn_fdot2(qa0, as_h2(Ka.x), da, false);
                db = __builtin_amdgcn_fdot2(qb0, as_h2(Kb.x), db, false);
                float pa = fast_exp2(da);
                float pb = fast_exp2(db);
                lsa += pa; lsb += pb;
                uint4 Va = *(const uint4*)(VHa + kk * QHSTR + hh * 8);
                uint4 Vb = *(const uint4*)(VHb + kk * QHSTR + hh * 8);
                _Float16 pha = (_Float16)pa, phb = (_Float16)pb;
                half2_t p2a = {pha, pha}, p2b = {phb, phb};
                aa0 += p2a * as_h2(Va.x); aa1 += p2a * as_h2(Va.y);
                aa2 += p2a * as_h2(Va.z); aa3 += p2a * as_h2(Va.w);
                ab0 += p2b * as_h2(Vb.x); ab1 += p2b * as_h2(Vb.y);
                ab2 += p2b * as_h2(Vb.z); ab3 += p2b * as_h2(Vb.w);
            }
            float inva = __builtin_amdgcn_rcpf(lsa);
            float invb = __builtin_amdgcn_rcpf(lsb);
            unsigned short* opa = HB[0] + s * 72 + hh * 7;
            unsigned short* opb = HB[1] + s * 72 + hh * 7;
            opa[0] = f2bf_t((float)aa0.x * inva); opa[1] = f2bf_t((float)aa0.y * inva);
            opa[2] = f2bf_t((float)aa1.x * inva); opa[3] = f2bf_t((float)aa1.y * inva);
            opa[4] = f2bf_t((float)aa2.x * inva); opa[5] = f2bf_t((float)aa2.y * inva);
            opa[6] = f2bf_t((float)aa3.x * inva);
            opb[0] = f2bf_t((float)ab0.x * invb); opb[1] = f2bf_t((float)ab0.y * invb);
            opb[2] = f2bf_t((float)ab1.x * invb); opb[3] = f2bf_t((float)ab1.y * invb);
            opb[4] = f2bf_t((float)ab2.x * invb); opb[5] = f2bf_t((float)ab2.y * invb);
            opb[6] = f2bf_t((float)ab3.x * invb);
        }
        __syncthreads();

        // ---- x += o @ Wo (shared B-frags, clamped A rows) ----
        {
            short8 a[2][2][2];
            #pragma unroll
            for (int ss = 0; ss < 2; ss++)
                #pragma unroll
                for (int ks = 0; ks < 2; ks++) {
                    a[ss][0][ks] = *(const short8*)(HB[ss] + nl * 72 + ks * 32 + quad * 8);
                    a[ss][1][ks] = *(const short8*)(HB[ss] + rA1 * 72 + ks * 32 + quad * 8);
                }
            const unsigned short* bp = ws + (((size_t)(l * 4 + 3)) << 12) + (((size_t)col) << 6) + quad * 8;
            short8 b0f = *(const short8*)(bp);
            short8 b1f = *(const short8*)(bp + 32);
            #pragma unroll
            for (int ss = 0; ss < 2; ss++) {
                f32x4 acc0 = {0, 0, 0, 0}, acc1 = {0, 0, 0, 0};
                acc0 = __builtin_amdgcn_mfma_f32_16x16x32_bf16(a[ss][0][0], b0f, acc0, 0, 0, 0);
                acc0 = __builtin_amdgcn_mfma_f32_16x16x32_bf16(a[ss][0][1], b1f, acc0, 0, 0, 0);
                acc1 = __builtin_amdgcn_mfma_f32_16x16x32_bf16(a[ss][1][0], b0f, acc1, 0, 0, 0);
                acc1 = __builtin_amdgcn_mfma_f32_16x16x32_bf16(a[ss][1][1], b1f, acc1, 0, 0, 0);
                if (col < 56) {
                    #pragma unroll
                    for (int r = 0; r < 4; r++) {
                        int row0 = quad * 4 + r;
                        XS[ss][row0 * XSTR + col] += acc0[r];
                        int row1 = 16 + row0;
                        if (row1 < 25) XS[ss][row1 * XSTR + col] += acc1[r];
                    }
                }
            }
        }
        __syncthreads();

        // ---- fused LN2 ----
        #pragma unroll
        for (int ss = 0; ss < 2; ss++) {
            float x[7]; float sum = 0.f, sq = 0.f;
            if (ln_s < 25) {
                const float* xp = XS[ss] + ln_s * XSTR + ln_p * 7;
                #pragma unroll
                for (int j = 0; j < 7; j++) { x[j] = xp[j]; sum += x[j]; sq += x[j] * x[j]; }
            }
            #pragma unroll
            for (int off = 1; off < 8; off <<= 1) {
                sum += __shfl_xor(sum, off, 64);
                sq  += __shfl_xor(sq,  off, 64);
            }
            if (ln_s < 25) {
                float mean = sum * (1.0f / 56.0f);
                float rs = __builtin_amdgcn_rsqf(sq * (1.0f / 56.0f) - mean * mean + 1e-5f);
                unsigned short* hp = HB[ss] + ln_s * 72 + ln_p * 7;
                #pragma unroll
                for (int j = 0; j < 7; j++) {
                    int d = ln_p * 7 + j;
                    hp[j] = f2bf_t((x[j] - mean) * rs * g2[d] + e2[d]);
                }
            }
        }
        __syncthreads();

        // ---- FFN1: f = gelu(h @ W1 + b1) -> FB (shared B-frags, clamped A rows) ----
        {
            short8 a[2][2][2];
            #pragma unroll
            for (int ss = 0; ss < 2; ss++)
                #pragma unroll
                for (int ks = 0; ks < 2; ks++) {
                    a[ss][0][ks] = *(const short8*)(HB[ss] + nl * 72 + ks * 32 + quad * 8);
                    a[ss][1][ks] = *(const short8*)(HB[ss] + rA1 * 72 + ks * 32 + quad * 8);
                }
            for (int u = wid; u < 14; u += 4) {
                int c1 = u * 16 + nl;
                const unsigned short* bp = w1t_all + (((size_t)(l * 224 + c1)) << 6) + quad * 8;
                short8 b0f = *(const short8*)(bp);
                short8 b1f = *(const short8*)(bp + 32);
                float bias = b1[l * 224 + c1];
                #pragma unroll
                for (int ss = 0; ss < 2; ss++) {
                    f32x4 acc0 = {0, 0, 0, 0}, acc1 = {0, 0, 0, 0};
                    acc0 = __builtin_amdgcn_mfma_f32_16x16x32_bf16(a[ss][0][0], b0f, acc0, 0, 0, 0);
                    acc0 = __builtin_amdgcn_mfma_f32_16x16x32_bf16(a[ss][0][1], b1f, acc0, 0, 0, 0);
                    acc1 = __builtin_amdgcn_mfma_f32_16x16x32_bf16(a[ss][1][0], b0f, acc1, 0, 0, 0);
                    acc1 = __builtin_amdgcn_mfma_f32_16x16x32_bf16(a[ss][1][1], b1f, acc1, 0, 0, 0);
                    unsigned short* FB = UNI[ss];
                    #pragma unroll
                    for (int r = 0; r < 4; r++) {
                        int row0 = quad * 4 + r;
                        FB[row0 * FSTR + c1] = f2bf_t(gelu_sig(acc0[r] + bias));
                        int row1 = 16 + row0;
                        if (row1 < 25) FB[row1 * FSTR + c1] = f2bf_t(gelu_sig(acc1[r] + bias));
                    }
                }
            }
        }
        __syncthreads();

        // ---- FFN2: x += f @ W2 + b2 (K=224; shared B-frags; A-rows clamped) ----
        {
            const unsigned short* bp0 = w2t_all + ((size_t)(l * 64 + col)) * 224 + quad * 8;
            f32x4 acc0a = {0,0,0,0}, acc1a = {0,0,0,0}, acc0b = {0,0,0,0}, acc1b = {0,0,0,0};
            #pragma unroll
            for (int ks = 0; ks < 7; ks++) {
                short8 bfrag = *(const short8*)(bp0 + ks * 32);
                const unsigned short* FBa = UNI[0];
                const unsigned short* FBb = UNI[1];
                short8 a0a = *(const short8*)(FBa + nl * FSTR + ks * 32 + quad * 8);
                short8 a1a = *(const short8*)(FBa + rA1 * FSTR + ks * 32 + quad * 8);
                short8 a0b = *(const short8*)(FBb + nl * FSTR + ks * 32 + quad * 8);
                short8 a1b = *(const short8*)(FBb + rA1 * FSTR + ks * 32 + quad * 8);
                acc0a = __builtin_amdgcn_mfma_f32_16x16x32_bf16(a0a, bfrag, acc0a, 0, 0, 0);
                acc0b = __builtin_amdgcn_mfma_f32_16x16x32_bf16(a0b, bfrag, acc0b, 0, 0, 0);
                acc1a = __builtin_amdgcn_mfma_f32_16x16x32_bf16(a1a, bfrag, acc1a, 0, 0, 0);
                acc1b = __builtin_amdgcn_mfma_f32_16x16x32_bf16(a1b, bfrag, acc1b, 0, 0, 0);
            }
            if (col < 56) {
                float bias = b2[l * 56 + col];
                #pragma unroll
                for (int r = 0; r < 4; r++) {
                    int row0 = quad * 4 + r;
                    XS[0][row0 * XSTR + col] += acc0a[r] + bias;
                    XS[1][row0 * XSTR + col] += acc0b[r] + bias;
                    int row1 = 16 + row0;
                    if (row1 < 25) {
                        XS[0][row1 * XSTR + col] += acc1a[r] + bias;
                        XS[1][row1 * XSTR + col] += acc1b[r] + bias;
                    }
                }
            }
        }
        __syncthreads();
    }

    // ---- output: both samples ----
    for (int t = tid; t < 80; t += NTH) {
        int ss = t / 40, r = t - ss * 40;
        int s = r >> 3, j = r & 7;
        int bb = b0 + ss;
        if (bb < Btot) out[(bb * 5 + s) * 8 + j] = XS[ss][s * XSTR + 8 + j];
    }
}

extern "C" void kernel_launch(void* const* d_in, const int* in_sizes, int n_in,
                              void* d_out, int out_size, void* d_ws, size_t ws_size,
                              hipStream_t stream) {
    const float* nodes = (const float*)d_in[0];
    const float* edges = (const float*)d_in[1];
    const float* mask  = (const float*)d_in[2];
    const int B = in_sizes[0] / 120;
    const float* W_in = (const float*)d_in[4];
    const float* b_in = (const float*)d_in[5];
    const float* W_gp = (const float*)d_in[6];
    const float* b_gp = (const float*)d_in[7];
    const float* Wq   = (const float*)d_in[8];
    const float* Wk   = (const float*)d_in[9];
    const float* Wv   = (const float*)d_in[10];
    const float* Wo   = (const float*)d_in[11];
    const float* ln1g = (const float*)d_in[12];
    const float* ln1b = (const float*)d_in[13];
    const float* ln2g = (const float*)d_in[14];
    const float* ln2b = (const float*)d_in[15];
    const float* W1   = (const float*)d_in[16];
    const float* b1   = (const float*)d_in[17];
    const float* W2   = (const float*)d_in[18];
    const float* b2   = (const float*)d_in[19];
    float* out = (float*)d_out;
    const int L = in_sizes[8] / 3136;

    unsigned short* ws16 = (unsigned short*)d_ws;
    int prep_total = L * (16384 + 14336 + 14336);
    hipLaunchKernelGGL(prep_weights, dim3((prep_total + NTH - 1) / NTH), dim3(NTH), 0, stream,
                       Wq, Wk, Wv, Wo, W1, W2, ws16, L);

    hipLaunchKernelGGL(nbody_fused, dim3((B + 1) / 2), dim3(NTH), 0, stream,
                       nodes, edges, mask, W_in, b_in, W_gp, b_gp,
                       ln1g, ln1b, ln2g, ln2b, b1, b2, ws16, L, B, out);
}